// Round 13
// baseline (440.947 us; speedup 1.0000x reference)
//
#include <hip/hip_runtime.h>

// Problem constants
#define NT   365
#define NS   256
#define NH   256
#define NG   32
#define NR   16
#define HID  256
#define NX   38           // 6 + NG
#define M_   (NT*NS)      // 93440
#define MPAD (368*NS)     // 94208 (padded to 46 t-groups of 8)
#define TOUT (NT-NR+1)    // 350
#define TC   46           // t-groups of 8
#define PSEG ((size_t)1024*TC*512)   // u16 per seg plane

typedef __attribute__((ext_vector_type(8))) short short8;
typedef __attribute__((ext_vector_type(4))) short short4v;
typedef __attribute__((ext_vector_type(4))) float floatx4;
typedef unsigned short u16;

__device__ __forceinline__ u16 f2bf(float f) {
    unsigned u = __float_as_uint(f);
    u = (u + 0x7FFFu + ((u >> 16) & 1u)) >> 16;   // RNE
    return (u16)u;
}
__device__ __forceinline__ float bf2f(u16 u) {
    return __uint_as_float(((unsigned)u) << 16);
}
__device__ __forceinline__ float sigmoidf_(float x) { return 1.f / (1.f + __expf(-x)); }

// async global->LDS, 16B per lane; LDS dest = wave-uniform base + lane*16B
#define GLDS16(gp, lp) __builtin_amdgcn_global_load_lds(\
    (const __attribute__((address_space(1))) void*)(gp), \
    (__attribute__((address_space(3))) void*)(lp), 16, 0, 0)

// ---------------- k_prep: pre(365) + cvtT3(416) + mlp1(32) + fcT1(2944) = 3757 blocks ----------------
__global__ __launch_bounds__(256) void k_prep(const float* __restrict__ x,
                                              float* __restrict__ ps, float* __restrict__ plc,
                                              float* __restrict__ e2, float* __restrict__ out,
                                              const float* __restrict__ tw2, u16* __restrict__ w2tT,
                                              const float* __restrict__ fw2, u16* __restrict__ w2tW,
                                              const float* __restrict__ rw2, u16* __restrict__ w2tR,
                                              const float* __restrict__ xc,
                                              const float* __restrict__ wW, const float* __restrict__ bW,
                                              const float* __restrict__ wR, const float* __restrict__ bR,
                                              u16* __restrict__ h1W, u16* __restrict__ h1R,
                                              const float* __restrict__ tw1, const float* __restrict__ tb1,
                                              u16* __restrict__ h1b) {
    int bx = blockIdx.x, tid = threadIdx.x;
    if (bx < 365) {
        // ---- pre body (+ zero out) ----
        int m = bx * 256 + tid;
        if (m < TOUT*NS) out[m] = 0.f;
        float P  = x[m*6+0], E = x[m*6+1], T1 = x[m*6+2], T2 = x[m*6+3];
        float vf;
        if (T2 <= 0.f)      vf = 1.f;
        else if (T1 >= 0.f) vf = 0.f;
        else {
            float ratio = (T1 + T2) / (T2 - T1);
            ratio = fminf(fmaxf(ratio, -1.f), 1.f);
            vf = acosf(ratio) * (1.f / 3.1415f);
        }
        ps[m]  = P * vf;
        plc[m] = P * (1.f - vf);
        e2[m]  = 2.f * E;
    } else if (bx < 781) {
        // ---- cvtT3 body ----
        __shared__ u16 tile[64][65];
        int i2 = bx - 365;
        int bn_ = i2 % 104, bk = i2 / 104;
        const float* w; u16* wt; int N, bn;
        if (bn_ < 12)      { w = tw2; wt = w2tT; N = 768;  bn = bn_; }
        else if (bn_ < 40) { w = fw2; wt = w2tW; N = 1792; bn = bn_ - 12; }
        else               { w = rw2; wt = w2tR; N = 4096; bn = bn_ - 40; }
        for (int i = tid; i < 64*64; i += 256) {
            int kk = i >> 6, nn = i & 63;
            tile[nn][kk] = f2bf(w[(size_t)(bk*64 + kk)*N + bn*64 + nn]);
        }
        __syncthreads();
        for (int i = tid; i < 64*64; i += 256) {
            int nn = i >> 6, kk = i & 63;
            wt[(size_t)(bn*64 + nn)*256 + bk*64 + kk] = tile[nn][kk];
        }
    } else if (bx < 813) {
        // ---- mlp1 body ----
        int b = bx - 781;                       // 0..31: net*16 + grp
        int net = b >> 4, grp = b & 15;
        const float* w1 = net ? wR : wW;
        const float* b1 = net ? bR : bW;
        u16* o = net ? h1R : h1W;
        int s0 = grp * 16, j = tid;
        __shared__ float xs1[16][NG];
        for (int i = j; i < 16*NG; i += 256) xs1[i >> 5][i & 31] = xc[s0*NG + i];
        __syncthreads();
        float acc[16];
        float bb = b1[j];
#pragma unroll
        for (int si = 0; si < 16; ++si) acc[si] = bb;
        for (int g = 0; g < NG; ++g) {
            float w = w1[g*HID + j];
#pragma unroll
            for (int si = 0; si < 16; ++si) acc[si] += xs1[si][g] * w;
        }
#pragma unroll
        for (int si = 0; si < 16; ++si) o[(s0 + si)*256 + j] = f2bf(tanhf(acc[si]));
    } else {
        // ---- fcT1 body (independent of the rest of this launch) ----
        int m0 = (bx - 813) * 32;               // grid tail = MPAD/32 = 2944
        int j = tid;
        __shared__ float xs2[32][NX + 2];
        for (int idx = j; idx < 32*NX; idx += 256) {
            int rr = idx / NX, c = idx % NX;
            int m = m0 + rr;
            int mc = m < M_ ? m : M_ - 1;       // clamp pad rows
            int s = mc & (NS - 1);
            xs2[rr][c] = (c < 6) ? x[mc*6 + c] : xc[s*NG + (c - 6)];
        }
        __syncthreads();
        float acc[32];
        float b = tb1[j];
#pragma unroll
        for (int rr = 0; rr < 32; ++rr) acc[rr] = b;
        for (int g = 0; g < NX; ++g) {
            float w = tw1[g*HID + j];
#pragma unroll
            for (int rr = 0; rr < 32; ++rr) acc[rr] += xs2[rr][g] * w;
        }
#pragma unroll
        for (int rr = 0; rr < 32; ++rr)
            h1b[(size_t)(m0 + rr)*HID + j] = f2bf(tanhf(acc[rr]));
    }
}

// ---------------- k_mid: gemmS<0> (28) + gemmS<1> (64) = 92 blocks ----------------
__global__ __launch_bounds__(256) void k_mid(const u16* __restrict__ h1W, const u16* __restrict__ w2tW,
                                             const float* __restrict__ fb2, float* __restrict__ wlog,
                                             const u16* __restrict__ h1R, const u16* __restrict__ w2tR,
                                             const float* __restrict__ rb2, float* __restrict__ rbuf) {
    int bx = blockIdx.x, tid = threadIdx.x;
    int mode, bm, bn, Nn;
    const u16 *A, *B; const float* bias; float* outp;
    if (bx < 28) { mode = 0; bm = bx % 2;        bn = bx / 2;        Nn = 1792; A = h1W; B = w2tW; bias = fb2; outp = wlog; }
    else         { mode = 1; bm = (bx - 28) % 2; bn = (bx - 28) / 2; Nn = 4096; A = h1R; B = w2tR; bias = rb2; outp = rbuf; }
    int wave = tid >> 6, lane = tid & 63;
    __shared__ __align__(16) u16 As[128*32];
    __shared__ __align__(16) u16 Bs[128*32];
    floatx4 acc[4][4];
#pragma unroll
    for (int i = 0; i < 4; ++i)
#pragma unroll
        for (int jj = 0; jj < 4; ++jj) acc[i][jj] = (floatx4)(0.f);
    int m0 = bm*128, n0 = bn*128;
    int rA = tid >> 2, cA = (tid & 3) * 8;
    int wm = (wave >> 1)*64, wn = (wave & 1)*64, lr = lane & 15, lq = lane >> 4;
    for (int k0 = 0; k0 < 256; k0 += 32) {
        short8 a0  = *(const short8*)(A + (m0 + rA     )*256 + k0 + cA);
        short8 a1  = *(const short8*)(A + (m0 + rA + 64)*256 + k0 + cA);
        short8 bv0 = *(const short8*)(B + (n0 + rA     )*256 + k0 + cA);
        short8 bv1 = *(const short8*)(B + (n0 + rA + 64)*256 + k0 + cA);
        __syncthreads();
        *(short8*)(As + rA*32 + cA)        = a0;
        *(short8*)(As + (rA + 64)*32 + cA) = a1;
        *(short8*)(Bs + rA*32 + cA)        = bv0;
        *(short8*)(Bs + (rA + 64)*32 + cA) = bv1;
        __syncthreads();
        short8 af[4], bf[4];
#pragma unroll
        for (int i = 0; i < 4; ++i)
            af[i] = *(const short8*)(As + (wm + i*16 + lr)*32 + lq*8);
#pragma unroll
        for (int jj = 0; jj < 4; ++jj)
            bf[jj] = *(const short8*)(Bs + (wn + jj*16 + lr)*32 + lq*8);
#pragma unroll
        for (int i = 0; i < 4; ++i)
#pragma unroll
            for (int jj = 0; jj < 4; ++jj)
                acc[i][jj] = __builtin_amdgcn_mfma_f32_16x16x32_bf16(af[i], bf[jj], acc[i][jj], 0, 0, 0);
    }
#pragma unroll
    for (int jj = 0; jj < 4; ++jj) {
        int n_glob = n0 + wn + jj*16 + lr;
        float bv = bias[n_glob];
        int hg = (n0 + wn + jj*16) >> 4;
#pragma unroll
        for (int i = 0; i < 4; ++i) {
#pragma unroll
            for (int rr = 0; rr < 4; ++rr) {
                int m = m0 + wm + i*16 + lq*4 + rr;
                float v = acc[i][jj][rr] + bv;
                if (mode == 0) {
                    outp[(size_t)m*Nn + n_glob] = v;
                } else {
                    v = fmaxf(v, 0.f);
                    float mx = v;
#pragma unroll
                    for (int d = 1; d < 16; d <<= 1) mx = fmaxf(mx, __shfl_xor(mx, d, 64));
                    float e = __expf(v - mx);
                    float sm = e;
#pragma unroll
                    for (int d = 1; d < 16; d <<= 1) sm += __shfl_xor(sm, d, 64);
                    outp[(size_t)m*4096 + hg*16 + lr] = e / sm;
                }
            }
        }
    }
}

// ---------------- k_g2p: fcw_post (blocks 0..255) + gemm2 (blocks 256..4671) ----------------
// gemm2 interior byte-identical to the proven round-9 kernel; fcw_post reads wlog
// (now OUTSIDE the Pc overlay) so it can run concurrently with gemm2's Pc writes.
__global__ __launch_bounds__(256) void k_g2p(const u16* __restrict__ h1b,
                                             const u16* __restrict__ w2t,
                                             const float* __restrict__ b2,
                                             const float* __restrict__ plc,
                                             const float* __restrict__ e2,
                                             u16* __restrict__ Pc,
                                             const float* __restrict__ wlog,
                                             float* __restrict__ par) {
    __shared__ __align__(16) u16 As[128*32];    // 8 KB (red buffer aliases this)
    __shared__ __align__(16) u16 Bs[128*32];    // 8 KB
    int tid = threadIdx.x;

    if (blockIdx.x < 256) {
        // ---- fcw_post body ----
        float* red = (float*)As;
        int s = blockIdx.x, j = tid;
        const float* L = wlog + (size_t)s*1792;
        float o0 = L[j], o1 = L[256+j], o2 = L[512+j], o3 = L[768+j],
              o4 = L[1024+j], o5 = L[1280+j], o6 = L[1536+j];
        red[j] = o6; __syncthreads();
        for (int st = 128; st > 0; st >>= 1) {
            if (j < st) red[j] = fmaxf(red[j], red[j+st]);
            __syncthreads();
        }
        float mx = red[0]; __syncthreads();
        float e = __expf(o6 - mx);
        red[j] = e; __syncthreads();
        for (int st = 128; st > 0; st >>= 1) {
            if (j < st) red[j] += red[j+st];
            __syncthreads();
        }
        float ga = e / red[0];
        int idx = s*NH + j;
        par[0*65536 + idx] = sigmoidf_(o0);
        par[1*65536 + idx] = sigmoidf_(o1);
        par[2*65536 + idx] = 0.1f * sigmoidf_(o2);
        par[3*65536 + idx] = sigmoidf_(o3);
        par[4*65536 + idx] = __expf(2.f * o4);
        par[5*65536 + idx] = fmaxf(o5, 0.f);
        par[6*65536 + idx] = ga;
        return;
    }

    // ---- gemm2 body (round-9, proven) ----
    int i_ = blockIdx.x - 256;         // 0..4415; 256 = 0 mod 8 keeps XCD swizzle
    int chunk = i_ / 48, rem = i_ % 48;
    int pair = chunk*8 + (rem & 7);
    int nt = rem >> 3;                 // 0..5
    int tg = pair >> 4, sg = pair & 15;
    int wave = tid >> 6, lane = tid & 63;
    int lr = lane & 15, lq = lane >> 4;
    int wm = (wave >> 1)*64, wn = (wave & 1)*64;

    floatx4 acc[4][4];
#pragma unroll
    for (int i = 0; i < 4; ++i)
#pragma unroll
        for (int jj = 0; jj < 4; ++jj) acc[i][jj] = (floatx4)(0.f);

    int rq = lane >> 2;                // 0..15
    int cq = (lane & 3) * 8;
    int jA0 = wave*2, jA1 = wave*2 + 1;
    const u16* gA0 = h1b + ((size_t)(tg*8 + jA0)*256 + sg*16 + rq)*256 + cq;
    const u16* gA1 = h1b + ((size_t)(tg*8 + jA1)*256 + sg*16 + rq)*256 + cq;
    const u16* gB0 = w2t + ((size_t)(nt*128 + jA0*16 + rq))*256 + cq;
    const u16* gB1 = w2t + ((size_t)(nt*128 + jA1*16 + rq))*256 + cq;

    for (int k0 = 0; k0 < 256; k0 += 32) {
        __syncthreads();               // prev frag reads done
        GLDS16(gA0 + k0, As + jA0*512);
        GLDS16(gA1 + k0, As + jA1*512);
        GLDS16(gB0 + k0, Bs + jA0*512);
        GLDS16(gB1 + k0, Bs + jA1*512);
        __syncthreads();               // vmcnt drained -> LDS valid
        short8 af[4], bf[4];
#pragma unroll
        for (int i = 0; i < 4; ++i)
            af[i] = *(const short8*)(As + (wm + i*16 + lr)*32 + lq*8);
#pragma unroll
        for (int jj = 0; jj < 4; ++jj)
            bf[jj] = *(const short8*)(Bs + (wn + jj*16 + lr)*32 + lq*8);
#pragma unroll
        for (int i = 0; i < 4; ++i)
#pragma unroll
            for (int jj = 0; jj < 4; ++jj)
                acc[i][jj] = __builtin_amdgcn_mfma_f32_16x16x32_bf16(af[i], bf[jj], acc[i][jj], 0, 0, 0);
    }

    int seg = nt >> 1;
    int hb = (nt & 1)*128 + wn;
    int tj0 = (wave >> 1)*4;
    u16* plane = Pc + (size_t)seg * PSEG;
#pragma unroll
    for (int jj = 0; jj < 4; ++jj) {
        int h = hb + jj*16 + lr;
        float bias = b2[seg*256 + h];
#pragma unroll
        for (int rr = 0; rr < 4; ++rr) {
            int s = sg*16 + lq*4 + rr;
            short4v o4;
#pragma unroll
            for (int i = 0; i < 4; ++i) {
                int m = (tg*8 + tj0 + i)*256 + s;
                float v = acc[i][jj][rr] + bias;
                float o;
                if (seg == 0)      o = plc[m] * fminf(fmaxf(v*(1.f/3.f) + 0.5f, 0.f), 1.f);
                else if (seg == 1) o = e2[m] * fmaxf(v, 0.f);
                else               o = __expf(v);
                o4[i] = (short)f2bf(o);
            }
            int idx = s*256 + h;
            *(short4v*)(plane + ((size_t)(idx >> 6)*TC + tg)*512 + (idx & 63)*8 + tj0) = o4;
        }
    }
}

// ---------------- k_scanconv: scan + 16-tap conv; depth-3 prefetch, coalesced 1KB loads ----------------
__global__ __launch_bounds__(64, 1) void k_scanconv(const u16* __restrict__ Pc,
                                                    const float* __restrict__ ps,
                                                    const float* __restrict__ par,
                                                    const float* __restrict__ r,
                                                    float* __restrict__ out) {
    int g = blockIdx.x;                // 1024 groups of 64 (s,h) pairs
    int lane = threadIdx.x;
    int idx = g*64 + lane;
    int s = idx >> 8;
    __shared__ float s_ps[NT];
    for (int t = lane; t < NT; t += 64) s_ps[t] = ps[t*NS + s];
    float kp = par[idx], ks_ = par[65536+idx], kg = par[2*65536+idx],
          gp = par[3*65536+idx], gL = par[4*65536+idx], qb = par[5*65536+idx],
          ga = par[6*65536+idx];
    float rt[NR];
#pragma unroll
    for (int k = 0; k < NR; ++k) rt[k] = r[(size_t)idx*NR + k] * ga;
    __syncthreads();

    const u16* b0 = Pc + 0*PSEG + (size_t)g*TC*512 + lane*8;
    const u16* b1 = Pc + 1*PSEG + (size_t)g*TC*512 + lane*8;
    const u16* b2p= Pc + 2*PSEG + (size_t)g*TC*512 + lane*8;

    union U8 { short8 v; u16 u[8]; };
    U8 c0[6], c1[6], c2[6], c3[6];
#pragma unroll
    for (int hc = 0; hc < 2; ++hc) {
        c0[0 + hc].v = *(const short8*)(b0 + hc*512);
        c0[2 + hc].v = *(const short8*)(b1 + hc*512);
        c0[4 + hc].v = *(const short8*)(b2p + hc*512);
        c1[0 + hc].v = *(const short8*)(b0 + (2 + hc)*512);
        c1[2 + hc].v = *(const short8*)(b1 + (2 + hc)*512);
        c1[4 + hc].v = *(const short8*)(b2p + (2 + hc)*512);
        c2[0 + hc].v = *(const short8*)(b0 + (4 + hc)*512);
        c2[2 + hc].v = *(const short8*)(b1 + (4 + hc)*512);
        c2[4 + hc].v = *(const short8*)(b2p + (4 + hc)*512);
    }
    float Sf = 0.f, Ss = 0.f, Sg = 0.f;
    float qwin[16];
#pragma unroll
    for (int k = 0; k < 16; ++k) qwin[k] = 0.f;

    for (int blk = 0; blk < 23; ++blk) {
        int tbase = blk * 16;
        if (blk < 20) {                // depth-3 prefetch: chunk blk+3
            size_t o = (size_t)(2*blk + 6)*512;
#pragma unroll
            for (int hc = 0; hc < 2; ++hc) {
                c3[0 + hc].v = *(const short8*)(b0 + o + hc*512);
                c3[2 + hc].v = *(const short8*)(b1 + o + hc*512);
                c3[4 + hc].v = *(const short8*)(b2p + o + hc*512);
            }
        }
        float cv[16];
#pragma unroll
        for (int j = 0; j < 16; ++j) cv[j] = 0.f;
#pragma unroll
        for (int j = 0; j < 16; ++j) {
            int t = tbase + j;
            if (t < NT) {
                float pl = bf2f(c0[0 + (j>>3)].u[j&7]);
                float ev = bf2f(c0[2 + (j>>3)].u[j&7]);
                float fm = bf2f(c0[4 + (j>>3)].u[j&7]);
                float fs = s_ps[t];
                float qf = fminf(Sf + fs, fm);
                Sf = fmaxf(Sf + fs - fm, 0.f);
                float H = fmaxf(Ss + pl + qf - ev, 0.f);
                float qp = fmaxf(kp * (H - gL), 0.f);
                float qsa = ks_ * fminf(H, gL);
                Ss = H - qp - qsa;
                float qsg = qsa * gp;
                float qs = qsa - qsg;
                float qg = kg * (Sg + qsg) + qb;
                Sg = (1.f - kg) * (Sg + qsg) - qb;
                float q = qp + qs + qg;
                qwin[j] = q;                 // slot t & 15 == j
                if (t >= 15) {
                    float c = 0.f;
#pragma unroll
                    for (int k = 0; k < 16; ++k) c += rt[k] * qwin[(j + 1 + k) & 15];
                    cv[j] = c;               // ga folded into rt
                }
            }
        }
#pragma unroll
        for (int pq = 0; pq < 6; ++pq) { c0[pq] = c1[pq]; c1[pq] = c2[pq]; c2[pq] = c3[pq]; }

#pragma unroll
        for (int d = 1; d < 64; d <<= 1) {
#pragma unroll
            for (int j = 0; j < 16; ++j) cv[j] += __shfl_xor(cv[j], d, 64);
        }
        float myv = 0.f;
#pragma unroll
        for (int j = 0; j < 16; ++j) myv = (lane == j) ? cv[j] : myv;
        int tout = tbase + lane - 15;
        if (lane < 16 && tout >= 0 && tout < TOUT)
            atomicAdd(out + tout*NS + s, myv);
    }
}

// ---------------- launch ----------------
extern "C" void kernel_launch(void* const* d_in, const int* in_sizes, int n_in,
                              void* d_out, int out_size, void* d_ws, size_t ws_size,
                              hipStream_t stream) {
    const float* x   = (const float*)d_in[0];
    const float* xc  = (const float*)d_in[1];
    const float* fw1 = (const float*)d_in[2];
    const float* fb1 = (const float*)d_in[3];
    const float* fw2 = (const float*)d_in[4];
    const float* fb2 = (const float*)d_in[5];
    const float* tw1 = (const float*)d_in[6];
    const float* tb1 = (const float*)d_in[7];
    const float* tw2 = (const float*)d_in[8];
    const float* tb2 = (const float*)d_in[9];
    const float* rw1 = (const float*)d_in[10];
    const float* rb1 = (const float*)d_in[11];
    const float* rw2 = (const float*)d_in[12];
    const float* rb2 = (const float*)d_in[13];
    float* out = (float*)d_out;
    char* ws = (char*)d_ws;

    // workspace layout (bytes); peak = 202,326,016 (wlog moved out of Pc overlay)
    constexpr size_t OFF_PS    = 0;              //   376,832 (padded to MPAD)
    constexpr size_t OFF_PLC   = 376832;         //   376,832
    constexpr size_t OFF_E2    = 753664;         //   376,832
    constexpr size_t OFF_PAR   = 1130496;        // 1,835,008
    constexpr size_t OFF_R     = 2965504;        // 4,194,304
    constexpr size_t OFF_W2TT  = 7159808;        //   393,216
    constexpr size_t OFF_H1B   = 7553024;        // 48,234,496 (MPAD rows)
    constexpr size_t OFF_PC    = 55787520;       // 144,703,488 -> 200,491,008
    constexpr size_t OFF_WLOG  = 200491008;      // 1,835,008 -> 202,326,016 (own region)
    // overlays inside Pc region (dead before k_g2p writes Pc):
    constexpr size_t OFF_W2TW  = OFF_PC + 0;           //   917,504
    constexpr size_t OFF_W2TR  = OFF_PC + 917504;      // 2,097,152
    constexpr size_t OFF_H1W   = OFF_PC + 3014656;     //   131,072
    constexpr size_t OFF_H1R   = OFF_PC + 3145728;     //   131,072

    float* ps    = (float*)(ws + OFF_PS);
    float* plc   = (float*)(ws + OFF_PLC);
    float* e2    = (float*)(ws + OFF_E2);
    float* par   = (float*)(ws + OFF_PAR);
    float* rbuf  = (float*)(ws + OFF_R);
    u16*   w2tT  = (u16*)(ws + OFF_W2TT);
    u16*   h1b   = (u16*)(ws + OFF_H1B);
    u16*   Pc    = (u16*)(ws + OFF_PC);
    float* wlog  = (float*)(ws + OFF_WLOG);
    u16*   w2tW  = (u16*)(ws + OFF_W2TW);
    u16*   w2tR  = (u16*)(ws + OFF_W2TR);
    u16*   h1W   = (u16*)(ws + OFF_H1W);
    u16*   h1R   = (u16*)(ws + OFF_H1R);

    k_prep     <<<3757, 256, 0, stream>>>(x, ps, plc, e2, out,
                                          tw2, w2tT, fw2, w2tW, rw2, w2tR,
                                          xc, fw1, fb1, rw1, rb1, h1W, h1R,
                                          tw1, tb1, h1b);
    k_mid      <<<92, 256, 0, stream>>>(h1W, w2tW, fb2, wlog,
                                        h1R, w2tR, rb2, rbuf);
    k_g2p      <<<256 + TC*16*6, 256, 0, stream>>>(h1b, w2tT, tb2, plc, e2, Pc, wlog, par);
    k_scanconv <<<1024, 64, 0, stream>>>(Pc, ps, par, rbuf, out);
}

// Round 14
// 370.172 us; speedup vs baseline: 1.1912x; 1.1912x over previous
//
#include <hip/hip_runtime.h>

// Problem constants
#define NT   365
#define NS   256
#define NH   256
#define NG   32
#define NR   16
#define HID  256
#define NX   38           // 6 + NG
#define M_   (NT*NS)      // 93440
#define MPAD (368*NS)     // 94208 (padded to 46 t-groups of 8)
#define TOUT (NT-NR+1)    // 350
#define TC   46           // t-groups of 8
#define PSEG ((size_t)1024*TC*512)   // u16 per seg plane

typedef __attribute__((ext_vector_type(8))) short short8;
typedef __attribute__((ext_vector_type(4))) short short4v;
typedef __attribute__((ext_vector_type(4))) float floatx4;
typedef unsigned short u16;

__device__ __forceinline__ u16 f2bf(float f) {
    unsigned u = __float_as_uint(f);
    u = (u + 0x7FFFu + ((u >> 16) & 1u)) >> 16;   // RNE
    return (u16)u;
}
__device__ __forceinline__ float bf2f(u16 u) {
    return __uint_as_float(((unsigned)u) << 16);
}
__device__ __forceinline__ float sigmoidf_(float x) { return 1.f / (1.f + __expf(-x)); }

// async global->LDS, 16B per lane; LDS dest = wave-uniform base + lane*16B
#define GLDS16(gp, lp) __builtin_amdgcn_global_load_lds(\
    (const __attribute__((address_space(1))) void*)(gp), \
    (__attribute__((address_space(3))) void*)(lp), 16, 0, 0)

// ---------------- k_prep: pre(365) + cvtT3(416) + mlp1(32) = 813 blocks (R12-proven) ----------------
__global__ __launch_bounds__(256) void k_prep(const float* __restrict__ x,
                                              float* __restrict__ ps, float* __restrict__ plc,
                                              float* __restrict__ e2, float* __restrict__ out,
                                              const float* __restrict__ tw2, u16* __restrict__ w2tT,
                                              const float* __restrict__ fw2, u16* __restrict__ w2tW,
                                              const float* __restrict__ rw2, u16* __restrict__ w2tR,
                                              const float* __restrict__ xc,
                                              const float* __restrict__ wW, const float* __restrict__ bW,
                                              const float* __restrict__ wR, const float* __restrict__ bR,
                                              u16* __restrict__ h1W, u16* __restrict__ h1R) {
    int bx = blockIdx.x, tid = threadIdx.x;
    if (bx < 365) {
        // ---- pre body (+ zero out) ----
        int m = bx * 256 + tid;
        if (m < TOUT*NS) out[m] = 0.f;
        float P  = x[m*6+0], E = x[m*6+1], T1 = x[m*6+2], T2 = x[m*6+3];
        float vf;
        if (T2 <= 0.f)      vf = 1.f;
        else if (T1 >= 0.f) vf = 0.f;
        else {
            float ratio = (T1 + T2) / (T2 - T1);
            ratio = fminf(fmaxf(ratio, -1.f), 1.f);
            vf = acosf(ratio) * (1.f / 3.1415f);
        }
        ps[m]  = P * vf;
        plc[m] = P * (1.f - vf);
        e2[m]  = 2.f * E;
    } else if (bx < 781) {
        // ---- cvtT3 body ----
        __shared__ u16 tile[64][65];
        int i2 = bx - 365;
        int bn_ = i2 % 104, bk = i2 / 104;
        const float* w; u16* wt; int N, bn;
        if (bn_ < 12)      { w = tw2; wt = w2tT; N = 768;  bn = bn_; }
        else if (bn_ < 40) { w = fw2; wt = w2tW; N = 1792; bn = bn_ - 12; }
        else               { w = rw2; wt = w2tR; N = 4096; bn = bn_ - 40; }
        for (int i = tid; i < 64*64; i += 256) {
            int kk = i >> 6, nn = i & 63;
            tile[nn][kk] = f2bf(w[(size_t)(bk*64 + kk)*N + bn*64 + nn]);
        }
        __syncthreads();
        for (int i = tid; i < 64*64; i += 256) {
            int nn = i >> 6, kk = i & 63;
            wt[(size_t)(bn*64 + nn)*256 + bk*64 + kk] = tile[nn][kk];
        }
    } else {
        // ---- mlp1 body ----
        int b = bx - 781;                       // 0..31: net*16 + grp
        int net = b >> 4, grp = b & 15;
        const float* w1 = net ? wR : wW;
        const float* b1 = net ? bR : bW;
        u16* o = net ? h1R : h1W;
        int s0 = grp * 16, j = tid;
        __shared__ float xs1[16][NG];
        for (int i = j; i < 16*NG; i += 256) xs1[i >> 5][i & 31] = xc[s0*NG + i];
        __syncthreads();
        float acc[16];
        float bb = b1[j];
#pragma unroll
        for (int si = 0; si < 16; ++si) acc[si] = bb;
        for (int g = 0; g < NG; ++g) {
            float w = w1[g*HID + j];
#pragma unroll
            for (int si = 0; si < 16; ++si) acc[si] += xs1[si][g] * w;
        }
#pragma unroll
        for (int si = 0; si < 16; ++si) o[(s0 + si)*256 + j] = f2bf(tanhf(acc[si]));
    }
}

// ---------------- k_mid: gemmS<0>(28) + gemmS<1>(64) + fcT1(2944) = 3036 blocks (R12-proven) ----------------
__global__ __launch_bounds__(256) void k_mid(const u16* __restrict__ h1W, const u16* __restrict__ w2tW,
                                             const float* __restrict__ fb2, float* __restrict__ wlog,
                                             const u16* __restrict__ h1R, const u16* __restrict__ w2tR,
                                             const float* __restrict__ rb2, float* __restrict__ rbuf,
                                             const float* __restrict__ x, const float* __restrict__ xc,
                                             const float* __restrict__ tw1, const float* __restrict__ tb1,
                                             u16* __restrict__ h1b) {
    int bx = blockIdx.x, tid = threadIdx.x;
    if (bx < 92) {
        // ---- gemmS body (mode 0: bx<28, mode 1: else) ----
        int mode, bm, bn, Nn;
        const u16 *A, *B; const float* bias; float* outp;
        if (bx < 28) { mode = 0; bm = bx % 2;        bn = bx / 2;        Nn = 1792; A = h1W; B = w2tW; bias = fb2; outp = wlog; }
        else         { mode = 1; bm = (bx - 28) % 2; bn = (bx - 28) / 2; Nn = 4096; A = h1R; B = w2tR; bias = rb2; outp = rbuf; }
        int wave = tid >> 6, lane = tid & 63;
        __shared__ __align__(16) u16 As[128*32];
        __shared__ __align__(16) u16 Bs[128*32];
        floatx4 acc[4][4];
#pragma unroll
        for (int i = 0; i < 4; ++i)
#pragma unroll
            for (int jj = 0; jj < 4; ++jj) acc[i][jj] = (floatx4)(0.f);
        int m0 = bm*128, n0 = bn*128;
        int rA = tid >> 2, cA = (tid & 3) * 8;
        int wm = (wave >> 1)*64, wn = (wave & 1)*64, lr = lane & 15, lq = lane >> 4;
        for (int k0 = 0; k0 < 256; k0 += 32) {
            short8 a0  = *(const short8*)(A + (m0 + rA     )*256 + k0 + cA);
            short8 a1  = *(const short8*)(A + (m0 + rA + 64)*256 + k0 + cA);
            short8 bv0 = *(const short8*)(B + (n0 + rA     )*256 + k0 + cA);
            short8 bv1 = *(const short8*)(B + (n0 + rA + 64)*256 + k0 + cA);
            __syncthreads();
            *(short8*)(As + rA*32 + cA)        = a0;
            *(short8*)(As + (rA + 64)*32 + cA) = a1;
            *(short8*)(Bs + rA*32 + cA)        = bv0;
            *(short8*)(Bs + (rA + 64)*32 + cA) = bv1;
            __syncthreads();
            short8 af[4], bf[4];
#pragma unroll
            for (int i = 0; i < 4; ++i)
                af[i] = *(const short8*)(As + (wm + i*16 + lr)*32 + lq*8);
#pragma unroll
            for (int jj = 0; jj < 4; ++jj)
                bf[jj] = *(const short8*)(Bs + (wn + jj*16 + lr)*32 + lq*8);
#pragma unroll
            for (int i = 0; i < 4; ++i)
#pragma unroll
                for (int jj = 0; jj < 4; ++jj)
                    acc[i][jj] = __builtin_amdgcn_mfma_f32_16x16x32_bf16(af[i], bf[jj], acc[i][jj], 0, 0, 0);
        }
#pragma unroll
        for (int jj = 0; jj < 4; ++jj) {
            int n_glob = n0 + wn + jj*16 + lr;
            float bv = bias[n_glob];
            int hg = (n0 + wn + jj*16) >> 4;
#pragma unroll
            for (int i = 0; i < 4; ++i) {
#pragma unroll
                for (int rr = 0; rr < 4; ++rr) {
                    int m = m0 + wm + i*16 + lq*4 + rr;
                    float v = acc[i][jj][rr] + bv;
                    if (mode == 0) {
                        outp[(size_t)m*Nn + n_glob] = v;
                    } else {
                        v = fmaxf(v, 0.f);
                        float mx = v;
#pragma unroll
                        for (int d = 1; d < 16; d <<= 1) mx = fmaxf(mx, __shfl_xor(mx, d, 64));
                        float e = __expf(v - mx);
                        float sm = e;
#pragma unroll
                        for (int d = 1; d < 16; d <<= 1) sm += __shfl_xor(sm, d, 64);
                        outp[(size_t)m*4096 + hg*16 + lr] = e / sm;
                    }
                }
            }
        }
    } else {
        // ---- fcT1 body ----
        int m0 = (bx - 92) * 32;
        int j = tid;
        __shared__ float xs[32][NX + 2];
        for (int idx = j; idx < 32*NX; idx += 256) {
            int rr = idx / NX, c = idx % NX;
            int m = m0 + rr;
            int mc = m < M_ ? m : M_ - 1;
            int s = mc & (NS - 1);
            xs[rr][c] = (c < 6) ? x[mc*6 + c] : xc[s*NG + (c - 6)];
        }
        __syncthreads();
        float acc[32];
        float b = tb1[j];
#pragma unroll
        for (int rr = 0; rr < 32; ++rr) acc[rr] = b;
        for (int g = 0; g < NX; ++g) {
            float w = tw1[g*HID + j];
#pragma unroll
            for (int rr = 0; rr < 32; ++rr) acc[rr] += xs[rr][g] * w;
        }
#pragma unroll
        for (int rr = 0; rr < 32; ++rr)
            h1b[(size_t)(m0 + rr)*HID + j] = f2bf(tanhf(acc[rr]));
    }
}

// ---------------- k_g2p: fcw_post (blocks 0..255) + gemm2 (blocks 256..4671) (R13-proven) ----------------
__global__ __launch_bounds__(256) void k_g2p(const u16* __restrict__ h1b,
                                             const u16* __restrict__ w2t,
                                             const float* __restrict__ b2,
                                             const float* __restrict__ plc,
                                             const float* __restrict__ e2,
                                             u16* __restrict__ Pc,
                                             const float* __restrict__ wlog,
                                             float* __restrict__ par) {
    __shared__ __align__(16) u16 As[128*32];    // 8 KB (red buffer aliases this)
    __shared__ __align__(16) u16 Bs[128*32];    // 8 KB
    int tid = threadIdx.x;

    if (blockIdx.x < 256) {
        // ---- fcw_post body ----
        float* red = (float*)As;
        int s = blockIdx.x, j = tid;
        const float* L = wlog + (size_t)s*1792;
        float o0 = L[j], o1 = L[256+j], o2 = L[512+j], o3 = L[768+j],
              o4 = L[1024+j], o5 = L[1280+j], o6 = L[1536+j];
        red[j] = o6; __syncthreads();
        for (int st = 128; st > 0; st >>= 1) {
            if (j < st) red[j] = fmaxf(red[j], red[j+st]);
            __syncthreads();
        }
        float mx = red[0]; __syncthreads();
        float e = __expf(o6 - mx);
        red[j] = e; __syncthreads();
        for (int st = 128; st > 0; st >>= 1) {
            if (j < st) red[j] += red[j+st];
            __syncthreads();
        }
        float ga = e / red[0];
        int idx = s*NH + j;
        par[0*65536 + idx] = sigmoidf_(o0);
        par[1*65536 + idx] = sigmoidf_(o1);
        par[2*65536 + idx] = 0.1f * sigmoidf_(o2);
        par[3*65536 + idx] = sigmoidf_(o3);
        par[4*65536 + idx] = __expf(2.f * o4);
        par[5*65536 + idx] = fmaxf(o5, 0.f);
        par[6*65536 + idx] = ga;
        return;
    }

    // ---- gemm2 body (round-9, proven) ----
    int i_ = blockIdx.x - 256;         // 0..4415; 256 = 0 mod 8 keeps XCD swizzle
    int chunk = i_ / 48, rem = i_ % 48;
    int pair = chunk*8 + (rem & 7);
    int nt = rem >> 3;                 // 0..5
    int tg = pair >> 4, sg = pair & 15;
    int wave = tid >> 6, lane = tid & 63;
    int lr = lane & 15, lq = lane >> 4;
    int wm = (wave >> 1)*64, wn = (wave & 1)*64;

    floatx4 acc[4][4];
#pragma unroll
    for (int i = 0; i < 4; ++i)
#pragma unroll
        for (int jj = 0; jj < 4; ++jj) acc[i][jj] = (floatx4)(0.f);

    int rq = lane >> 2;                // 0..15
    int cq = (lane & 3) * 8;
    int jA0 = wave*2, jA1 = wave*2 + 1;
    const u16* gA0 = h1b + ((size_t)(tg*8 + jA0)*256 + sg*16 + rq)*256 + cq;
    const u16* gA1 = h1b + ((size_t)(tg*8 + jA1)*256 + sg*16 + rq)*256 + cq;
    const u16* gB0 = w2t + ((size_t)(nt*128 + jA0*16 + rq))*256 + cq;
    const u16* gB1 = w2t + ((size_t)(nt*128 + jA1*16 + rq))*256 + cq;

    for (int k0 = 0; k0 < 256; k0 += 32) {
        __syncthreads();               // prev frag reads done
        GLDS16(gA0 + k0, As + jA0*512);
        GLDS16(gA1 + k0, As + jA1*512);
        GLDS16(gB0 + k0, Bs + jA0*512);
        GLDS16(gB1 + k0, Bs + jA1*512);
        __syncthreads();               // vmcnt drained -> LDS valid
        short8 af[4], bf[4];
#pragma unroll
        for (int i = 0; i < 4; ++i)
            af[i] = *(const short8*)(As + (wm + i*16 + lr)*32 + lq*8);
#pragma unroll
        for (int jj = 0; jj < 4; ++jj)
            bf[jj] = *(const short8*)(Bs + (wn + jj*16 + lr)*32 + lq*8);
#pragma unroll
        for (int i = 0; i < 4; ++i)
#pragma unroll
            for (int jj = 0; jj < 4; ++jj)
                acc[i][jj] = __builtin_amdgcn_mfma_f32_16x16x32_bf16(af[i], bf[jj], acc[i][jj], 0, 0, 0);
    }

    int seg = nt >> 1;
    int hb = (nt & 1)*128 + wn;
    int tj0 = (wave >> 1)*4;
    u16* plane = Pc + (size_t)seg * PSEG;
#pragma unroll
    for (int jj = 0; jj < 4; ++jj) {
        int h = hb + jj*16 + lr;
        float bias = b2[seg*256 + h];
#pragma unroll
        for (int rr = 0; rr < 4; ++rr) {
            int s = sg*16 + lq*4 + rr;
            short4v o4;
#pragma unroll
            for (int i = 0; i < 4; ++i) {
                int m = (tg*8 + tj0 + i)*256 + s;
                float v = acc[i][jj][rr] + bias;
                float o;
                if (seg == 0)      o = plc[m] * fminf(fmaxf(v*(1.f/3.f) + 0.5f, 0.f), 1.f);
                else if (seg == 1) o = e2[m] * fmaxf(v, 0.f);
                else               o = __expf(v);
                o4[i] = (short)f2bf(o);
            }
            int idx = s*256 + h;
            *(short4v*)(plane + ((size_t)(idx >> 6)*TC + tg)*512 + (idx & 63)*8 + tj0) = o4;
        }
    }
}

// ---------------- k_scanconv: scan + 16-tap conv; depth-3 prefetch, coalesced 1KB loads ----------------
__global__ __launch_bounds__(64, 1) void k_scanconv(const u16* __restrict__ Pc,
                                                    const float* __restrict__ ps,
                                                    const float* __restrict__ par,
                                                    const float* __restrict__ r,
                                                    float* __restrict__ out) {
    int g = blockIdx.x;                // 1024 groups of 64 (s,h) pairs
    int lane = threadIdx.x;
    int idx = g*64 + lane;
    int s = idx >> 8;
    __shared__ float s_ps[NT];
    for (int t = lane; t < NT; t += 64) s_ps[t] = ps[t*NS + s];
    float kp = par[idx], ks_ = par[65536+idx], kg = par[2*65536+idx],
          gp = par[3*65536+idx], gL = par[4*65536+idx], qb = par[5*65536+idx],
          ga = par[6*65536+idx];
    float rt[NR];
#pragma unroll
    for (int k = 0; k < NR; ++k) rt[k] = r[(size_t)idx*NR + k] * ga;
    __syncthreads();

    const u16* b0 = Pc + 0*PSEG + (size_t)g*TC*512 + lane*8;
    const u16* b1 = Pc + 1*PSEG + (size_t)g*TC*512 + lane*8;
    const u16* b2p= Pc + 2*PSEG + (size_t)g*TC*512 + lane*8;

    union U8 { short8 v; u16 u[8]; };
    U8 c0[6], c1[6], c2[6], c3[6];
#pragma unroll
    for (int hc = 0; hc < 2; ++hc) {
        c0[0 + hc].v = *(const short8*)(b0 + hc*512);
        c0[2 + hc].v = *(const short8*)(b1 + hc*512);
        c0[4 + hc].v = *(const short8*)(b2p + hc*512);
        c1[0 + hc].v = *(const short8*)(b0 + (2 + hc)*512);
        c1[2 + hc].v = *(const short8*)(b1 + (2 + hc)*512);
        c1[4 + hc].v = *(const short8*)(b2p + (2 + hc)*512);
        c2[0 + hc].v = *(const short8*)(b0 + (4 + hc)*512);
        c2[2 + hc].v = *(const short8*)(b1 + (4 + hc)*512);
        c2[4 + hc].v = *(const short8*)(b2p + (4 + hc)*512);
    }
    float Sf = 0.f, Ss = 0.f, Sg = 0.f;
    float qwin[16];
#pragma unroll
    for (int k = 0; k < 16; ++k) qwin[k] = 0.f;

    for (int blk = 0; blk < 23; ++blk) {
        int tbase = blk * 16;
        if (blk < 20) {                // depth-3 prefetch: chunk blk+3
            size_t o = (size_t)(2*blk + 6)*512;
#pragma unroll
            for (int hc = 0; hc < 2; ++hc) {
                c3[0 + hc].v = *(const short8*)(b0 + o + hc*512);
                c3[2 + hc].v = *(const short8*)(b1 + o + hc*512);
                c3[4 + hc].v = *(const short8*)(b2p + o + hc*512);
            }
        }
        float cv[16];
#pragma unroll
        for (int j = 0; j < 16; ++j) cv[j] = 0.f;
#pragma unroll
        for (int j = 0; j < 16; ++j) {
            int t = tbase + j;
            if (t < NT) {
                float pl = bf2f(c0[0 + (j>>3)].u[j&7]);
                float ev = bf2f(c0[2 + (j>>3)].u[j&7]);
                float fm = bf2f(c0[4 + (j>>3)].u[j&7]);
                float fs = s_ps[t];
                float qf = fminf(Sf + fs, fm);
                Sf = fmaxf(Sf + fs - fm, 0.f);
                float H = fmaxf(Ss + pl + qf - ev, 0.f);
                float qp = fmaxf(kp * (H - gL), 0.f);
                float qsa = ks_ * fminf(H, gL);
                Ss = H - qp - qsa;
                float qsg = qsa * gp;
                float qs = qsa - qsg;
                float qg = kg * (Sg + qsg) + qb;
                Sg = (1.f - kg) * (Sg + qsg) - qb;
                float q = qp + qs + qg;
                qwin[j] = q;                 // slot t & 15 == j
                if (t >= 15) {
                    float c = 0.f;
#pragma unroll
                    for (int k = 0; k < 16; ++k) c += rt[k] * qwin[(j + 1 + k) & 15];
                    cv[j] = c;               // ga folded into rt
                }
            }
        }
#pragma unroll
        for (int pq = 0; pq < 6; ++pq) { c0[pq] = c1[pq]; c1[pq] = c2[pq]; c2[pq] = c3[pq]; }

#pragma unroll
        for (int d = 1; d < 64; d <<= 1) {
#pragma unroll
            for (int j = 0; j < 16; ++j) cv[j] += __shfl_xor(cv[j], d, 64);
        }
        float myv = 0.f;
#pragma unroll
        for (int j = 0; j < 16; ++j) myv = (lane == j) ? cv[j] : myv;
        int tout = tbase + lane - 15;
        if (lane < 16 && tout >= 0 && tout < TOUT)
            atomicAdd(out + tout*NS + s, myv);
    }
}

// ---------------- launch ----------------
extern "C" void kernel_launch(void* const* d_in, const int* in_sizes, int n_in,
                              void* d_out, int out_size, void* d_ws, size_t ws_size,
                              hipStream_t stream) {
    const float* x   = (const float*)d_in[0];
    const float* xc  = (const float*)d_in[1];
    const float* fw1 = (const float*)d_in[2];
    const float* fb1 = (const float*)d_in[3];
    const float* fw2 = (const float*)d_in[4];
    const float* fb2 = (const float*)d_in[5];
    const float* tw1 = (const float*)d_in[6];
    const float* tb1 = (const float*)d_in[7];
    const float* tw2 = (const float*)d_in[8];
    const float* tb2 = (const float*)d_in[9];
    const float* rw1 = (const float*)d_in[10];
    const float* rb1 = (const float*)d_in[11];
    const float* rw2 = (const float*)d_in[12];
    const float* rb2 = (const float*)d_in[13];
    float* out = (float*)d_out;
    char* ws = (char*)d_ws;

    // workspace layout (bytes); peak = 202,326,016 (wlog in own region)
    constexpr size_t OFF_PS    = 0;              //   376,832 (padded to MPAD)
    constexpr size_t OFF_PLC   = 376832;         //   376,832
    constexpr size_t OFF_E2    = 753664;         //   376,832
    constexpr size_t OFF_PAR   = 1130496;        // 1,835,008
    constexpr size_t OFF_R     = 2965504;        // 4,194,304
    constexpr size_t OFF_W2TT  = 7159808;        //   393,216
    constexpr size_t OFF_H1B   = 7553024;        // 48,234,496 (MPAD rows)
    constexpr size_t OFF_PC    = 55787520;       // 144,703,488 -> 200,491,008
    constexpr size_t OFF_WLOG  = 200491008;      // 1,835,008 -> 202,326,016 (own region)
    // overlays inside Pc region (dead before k_g2p writes Pc):
    constexpr size_t OFF_W2TW  = OFF_PC + 0;           //   917,504
    constexpr size_t OFF_W2TR  = OFF_PC + 917504;      // 2,097,152
    constexpr size_t OFF_H1W   = OFF_PC + 3014656;     //   131,072
    constexpr size_t OFF_H1R   = OFF_PC + 3145728;     //   131,072

    float* ps    = (float*)(ws + OFF_PS);
    float* plc   = (float*)(ws + OFF_PLC);
    float* e2    = (float*)(ws + OFF_E2);
    float* par   = (float*)(ws + OFF_PAR);
    float* rbuf  = (float*)(ws + OFF_R);
    u16*   w2tT  = (u16*)(ws + OFF_W2TT);
    u16*   h1b   = (u16*)(ws + OFF_H1B);
    u16*   Pc    = (u16*)(ws + OFF_PC);
    float* wlog  = (float*)(ws + OFF_WLOG);
    u16*   w2tW  = (u16*)(ws + OFF_W2TW);
    u16*   w2tR  = (u16*)(ws + OFF_W2TR);
    u16*   h1W   = (u16*)(ws + OFF_H1W);
    u16*   h1R   = (u16*)(ws + OFF_H1R);

    k_prep     <<<813, 256, 0, stream>>>(x, ps, plc, e2, out,
                                         tw2, w2tT, fw2, w2tW, rw2, w2tR,
                                         xc, fw1, fb1, rw1, rb1, h1W, h1R);
    k_mid      <<<3036, 256, 0, stream>>>(h1W, w2tW, fb2, wlog,
                                          h1R, w2tR, rb2, rbuf,
                                          x, xc, tw1, tb1, h1b);
    k_g2p      <<<256 + TC*16*6, 256, 0, stream>>>(h1b, w2tT, tb2, plc, e2, Pc, wlog, par);
    k_scanconv <<<1024, 64, 0, stream>>>(Pc, ps, par, rbuf, out);
}

// Round 15
// 338.400 us; speedup vs baseline: 1.3030x; 1.0939x over previous
//
#include <hip/hip_runtime.h>

// Problem constants
#define NT   365
#define NS   256
#define NH   256
#define NG   32
#define NR   16
#define HID  256
#define NX   38           // 6 + NG
#define M_   (NT*NS)      // 93440
#define MPAD (368*NS)     // 94208 (padded to 46 t-groups of 8)
#define TOUT (NT-NR+1)    // 350
#define TC   46           // t-groups of 8
#define PSEG ((size_t)1024*TC*512)   // u16 per seg plane

typedef __attribute__((ext_vector_type(8))) short short8;
typedef __attribute__((ext_vector_type(4))) short short4v;
typedef __attribute__((ext_vector_type(4))) float floatx4;
typedef unsigned short u16;

__device__ __forceinline__ u16 f2bf(float f) {
    unsigned u = __float_as_uint(f);
    u = (u + 0x7FFFu + ((u >> 16) & 1u)) >> 16;   // RNE
    return (u16)u;
}
__device__ __forceinline__ float bf2f(u16 u) {
    return __uint_as_float(((unsigned)u) << 16);
}
__device__ __forceinline__ float sigmoidf_(float x) { return 1.f / (1.f + __expf(-x)); }

// async global->LDS, 16B per lane; LDS dest = wave-uniform base + lane*16B
#define GLDS16(gp, lp) __builtin_amdgcn_global_load_lds(\
    (const __attribute__((address_space(1))) void*)(gp), \
    (__attribute__((address_space(3))) void*)(lp), 16, 0, 0)

// ---------------- k_prep: pre(365) + cvtT3(416) + mlp1(32) = 813 blocks (R12/R14-proven) ----------------
__global__ __launch_bounds__(256) void k_prep(const float* __restrict__ x,
                                              float* __restrict__ ps, float* __restrict__ plc,
                                              float* __restrict__ e2, float* __restrict__ out,
                                              const float* __restrict__ tw2, u16* __restrict__ w2tT,
                                              const float* __restrict__ fw2, u16* __restrict__ w2tW,
                                              const float* __restrict__ rw2, u16* __restrict__ w2tR,
                                              const float* __restrict__ xc,
                                              const float* __restrict__ wW, const float* __restrict__ bW,
                                              const float* __restrict__ wR, const float* __restrict__ bR,
                                              u16* __restrict__ h1W, u16* __restrict__ h1R) {
    int bx = blockIdx.x, tid = threadIdx.x;
    if (bx < 365) {
        // ---- pre body (+ zero out) ----
        int m = bx * 256 + tid;
        if (m < TOUT*NS) out[m] = 0.f;
        float P  = x[m*6+0], E = x[m*6+1], T1 = x[m*6+2], T2 = x[m*6+3];
        float vf;
        if (T2 <= 0.f)      vf = 1.f;
        else if (T1 >= 0.f) vf = 0.f;
        else {
            float ratio = (T1 + T2) / (T2 - T1);
            ratio = fminf(fmaxf(ratio, -1.f), 1.f);
            vf = acosf(ratio) * (1.f / 3.1415f);
        }
        ps[m]  = P * vf;
        plc[m] = P * (1.f - vf);
        e2[m]  = 2.f * E;
    } else if (bx < 781) {
        // ---- cvtT3 body ----
        __shared__ u16 tile[64][65];
        int i2 = bx - 365;
        int bn_ = i2 % 104, bk = i2 / 104;
        const float* w; u16* wt; int N, bn;
        if (bn_ < 12)      { w = tw2; wt = w2tT; N = 768;  bn = bn_; }
        else if (bn_ < 40) { w = fw2; wt = w2tW; N = 1792; bn = bn_ - 12; }
        else               { w = rw2; wt = w2tR; N = 4096; bn = bn_ - 40; }
        for (int i = tid; i < 64*64; i += 256) {
            int kk = i >> 6, nn = i & 63;
            tile[nn][kk] = f2bf(w[(size_t)(bk*64 + kk)*N + bn*64 + nn]);
        }
        __syncthreads();
        for (int i = tid; i < 64*64; i += 256) {
            int nn = i >> 6, kk = i & 63;
            wt[(size_t)(bn*64 + nn)*256 + bk*64 + kk] = tile[nn][kk];
        }
    } else {
        // ---- mlp1 body ----
        int b = bx - 781;                       // 0..31: net*16 + grp
        int net = b >> 4, grp = b & 15;
        const float* w1 = net ? wR : wW;
        const float* b1 = net ? bR : bW;
        u16* o = net ? h1R : h1W;
        int s0 = grp * 16, j = tid;
        __shared__ float xs1[16][NG];
        for (int i = j; i < 16*NG; i += 256) xs1[i >> 5][i & 31] = xc[s0*NG + i];
        __syncthreads();
        float acc[16];
        float bb = b1[j];
#pragma unroll
        for (int si = 0; si < 16; ++si) acc[si] = bb;
        for (int g = 0; g < NG; ++g) {
            float w = w1[g*HID + j];
#pragma unroll
            for (int si = 0; si < 16; ++si) acc[si] += xs1[si][g] * w;
        }
#pragma unroll
        for (int si = 0; si < 16; ++si) o[(s0 + si)*256 + j] = f2bf(tanhf(acc[si]));
    }
}

// ---------------- k_mid: gemmS<0>(28) + gemmS<1>(64) + fcT1(2944) = 3036 blocks (R12/R14-proven) ----------------
__global__ __launch_bounds__(256) void k_mid(const u16* __restrict__ h1W, const u16* __restrict__ w2tW,
                                             const float* __restrict__ fb2, float* __restrict__ wlog,
                                             const u16* __restrict__ h1R, const u16* __restrict__ w2tR,
                                             const float* __restrict__ rb2, float* __restrict__ rbuf,
                                             const float* __restrict__ x, const float* __restrict__ xc,
                                             const float* __restrict__ tw1, const float* __restrict__ tb1,
                                             u16* __restrict__ h1b) {
    int bx = blockIdx.x, tid = threadIdx.x;
    if (bx < 92) {
        // ---- gemmS body (mode 0: bx<28, mode 1: else) ----
        int mode, bm, bn, Nn;
        const u16 *A, *B; const float* bias; float* outp;
        if (bx < 28) { mode = 0; bm = bx % 2;        bn = bx / 2;        Nn = 1792; A = h1W; B = w2tW; bias = fb2; outp = wlog; }
        else         { mode = 1; bm = (bx - 28) % 2; bn = (bx - 28) / 2; Nn = 4096; A = h1R; B = w2tR; bias = rb2; outp = rbuf; }
        int wave = tid >> 6, lane = tid & 63;
        __shared__ __align__(16) u16 As[128*32];
        __shared__ __align__(16) u16 Bs[128*32];
        floatx4 acc[4][4];
#pragma unroll
        for (int i = 0; i < 4; ++i)
#pragma unroll
            for (int jj = 0; jj < 4; ++jj) acc[i][jj] = (floatx4)(0.f);
        int m0 = bm*128, n0 = bn*128;
        int rA = tid >> 2, cA = (tid & 3) * 8;
        int wm = (wave >> 1)*64, wn = (wave & 1)*64, lr = lane & 15, lq = lane >> 4;
        for (int k0 = 0; k0 < 256; k0 += 32) {
            short8 a0  = *(const short8*)(A + (m0 + rA     )*256 + k0 + cA);
            short8 a1  = *(const short8*)(A + (m0 + rA + 64)*256 + k0 + cA);
            short8 bv0 = *(const short8*)(B + (n0 + rA     )*256 + k0 + cA);
            short8 bv1 = *(const short8*)(B + (n0 + rA + 64)*256 + k0 + cA);
            __syncthreads();
            *(short8*)(As + rA*32 + cA)        = a0;
            *(short8*)(As + (rA + 64)*32 + cA) = a1;
            *(short8*)(Bs + rA*32 + cA)        = bv0;
            *(short8*)(Bs + (rA + 64)*32 + cA) = bv1;
            __syncthreads();
            short8 af[4], bf[4];
#pragma unroll
            for (int i = 0; i < 4; ++i)
                af[i] = *(const short8*)(As + (wm + i*16 + lr)*32 + lq*8);
#pragma unroll
            for (int jj = 0; jj < 4; ++jj)
                bf[jj] = *(const short8*)(Bs + (wn + jj*16 + lr)*32 + lq*8);
#pragma unroll
            for (int i = 0; i < 4; ++i)
#pragma unroll
                for (int jj = 0; jj < 4; ++jj)
                    acc[i][jj] = __builtin_amdgcn_mfma_f32_16x16x32_bf16(af[i], bf[jj], acc[i][jj], 0, 0, 0);
        }
#pragma unroll
        for (int jj = 0; jj < 4; ++jj) {
            int n_glob = n0 + wn + jj*16 + lr;
            float bv = bias[n_glob];
            int hg = (n0 + wn + jj*16) >> 4;
#pragma unroll
            for (int i = 0; i < 4; ++i) {
#pragma unroll
                for (int rr = 0; rr < 4; ++rr) {
                    int m = m0 + wm + i*16 + lq*4 + rr;
                    float v = acc[i][jj][rr] + bv;
                    if (mode == 0) {
                        outp[(size_t)m*Nn + n_glob] = v;
                    } else {
                        v = fmaxf(v, 0.f);
                        float mx = v;
#pragma unroll
                        for (int d = 1; d < 16; d <<= 1) mx = fmaxf(mx, __shfl_xor(mx, d, 64));
                        float e = __expf(v - mx);
                        float sm = e;
#pragma unroll
                        for (int d = 1; d < 16; d <<= 1) sm += __shfl_xor(sm, d, 64);
                        outp[(size_t)m*4096 + hg*16 + lr] = e / sm;
                    }
                }
            }
        }
    } else {
        // ---- fcT1 body ----
        int m0 = (bx - 92) * 32;
        int j = tid;
        __shared__ float xs[32][NX + 2];
        for (int idx = j; idx < 32*NX; idx += 256) {
            int rr = idx / NX, c = idx % NX;
            int m = m0 + rr;
            int mc = m < M_ ? m : M_ - 1;
            int s = mc & (NS - 1);
            xs[rr][c] = (c < 6) ? x[mc*6 + c] : xc[s*NG + (c - 6)];
        }
        __syncthreads();
        float acc[32];
        float b = tb1[j];
#pragma unroll
        for (int rr = 0; rr < 32; ++rr) acc[rr] = b;
        for (int g = 0; g < NX; ++g) {
            float w = tw1[g*HID + j];
#pragma unroll
            for (int rr = 0; rr < 32; ++rr) acc[rr] += xs[rr][g] * w;
        }
#pragma unroll
        for (int rr = 0; rr < 32; ++rr)
            h1b[(size_t)(m0 + rr)*HID + j] = f2bf(tanhf(acc[rr]));
    }
}

// ---------------- k_g2p: fcw_post (blocks 0..255) + gemm2 (blocks 256..4671) (R13/R14-proven) ----------------
__global__ __launch_bounds__(256) void k_g2p(const u16* __restrict__ h1b,
                                             const u16* __restrict__ w2t,
                                             const float* __restrict__ b2,
                                             const float* __restrict__ plc,
                                             const float* __restrict__ e2,
                                             u16* __restrict__ Pc,
                                             const float* __restrict__ wlog,
                                             float* __restrict__ par) {
    __shared__ __align__(16) u16 As[128*32];    // 8 KB (red buffer aliases this)
    __shared__ __align__(16) u16 Bs[128*32];    // 8 KB
    int tid = threadIdx.x;

    if (blockIdx.x < 256) {
        // ---- fcw_post body ----
        float* red = (float*)As;
        int s = blockIdx.x, j = tid;
        const float* L = wlog + (size_t)s*1792;
        float o0 = L[j], o1 = L[256+j], o2 = L[512+j], o3 = L[768+j],
              o4 = L[1024+j], o5 = L[1280+j], o6 = L[1536+j];
        red[j] = o6; __syncthreads();
        for (int st = 128; st > 0; st >>= 1) {
            if (j < st) red[j] = fmaxf(red[j], red[j+st]);
            __syncthreads();
        }
        float mx = red[0]; __syncthreads();
        float e = __expf(o6 - mx);
        red[j] = e; __syncthreads();
        for (int st = 128; st > 0; st >>= 1) {
            if (j < st) red[j] += red[j+st];
            __syncthreads();
        }
        float ga = e / red[0];
        int idx = s*NH + j;
        par[0*65536 + idx] = sigmoidf_(o0);
        par[1*65536 + idx] = sigmoidf_(o1);
        par[2*65536 + idx] = 0.1f * sigmoidf_(o2);
        par[3*65536 + idx] = sigmoidf_(o3);
        par[4*65536 + idx] = __expf(2.f * o4);
        par[5*65536 + idx] = fmaxf(o5, 0.f);
        par[6*65536 + idx] = ga;
        return;
    }

    // ---- gemm2 body (round-9, proven) ----
    int i_ = blockIdx.x - 256;         // 0..4415; 256 = 0 mod 8 keeps XCD swizzle
    int chunk = i_ / 48, rem = i_ % 48;
    int pair = chunk*8 + (rem & 7);
    int nt = rem >> 3;                 // 0..5
    int tg = pair >> 4, sg = pair & 15;
    int wave = tid >> 6, lane = tid & 63;
    int lr = lane & 15, lq = lane >> 4;
    int wm = (wave >> 1)*64, wn = (wave & 1)*64;

    floatx4 acc[4][4];
#pragma unroll
    for (int i = 0; i < 4; ++i)
#pragma unroll
        for (int jj = 0; jj < 4; ++jj) acc[i][jj] = (floatx4)(0.f);

    int rq = lane >> 2;                // 0..15
    int cq = (lane & 3) * 8;
    int jA0 = wave*2, jA1 = wave*2 + 1;
    const u16* gA0 = h1b + ((size_t)(tg*8 + jA0)*256 + sg*16 + rq)*256 + cq;
    const u16* gA1 = h1b + ((size_t)(tg*8 + jA1)*256 + sg*16 + rq)*256 + cq;
    const u16* gB0 = w2t + ((size_t)(nt*128 + jA0*16 + rq))*256 + cq;
    const u16* gB1 = w2t + ((size_t)(nt*128 + jA1*16 + rq))*256 + cq;

    for (int k0 = 0; k0 < 256; k0 += 32) {
        __syncthreads();               // prev frag reads done
        GLDS16(gA0 + k0, As + jA0*512);
        GLDS16(gA1 + k0, As + jA1*512);
        GLDS16(gB0 + k0, Bs + jA0*512);
        GLDS16(gB1 + k0, Bs + jA1*512);
        __syncthreads();               // vmcnt drained -> LDS valid
        short8 af[4], bf[4];
#pragma unroll
        for (int i = 0; i < 4; ++i)
            af[i] = *(const short8*)(As + (wm + i*16 + lr)*32 + lq*8);
#pragma unroll
        for (int jj = 0; jj < 4; ++jj)
            bf[jj] = *(const short8*)(Bs + (wn + jj*16 + lr)*32 + lq*8);
#pragma unroll
        for (int i = 0; i < 4; ++i)
#pragma unroll
            for (int jj = 0; jj < 4; ++jj)
                acc[i][jj] = __builtin_amdgcn_mfma_f32_16x16x32_bf16(af[i], bf[jj], acc[i][jj], 0, 0, 0);
    }

    int seg = nt >> 1;
    int hb = (nt & 1)*128 + wn;
    int tj0 = (wave >> 1)*4;
    u16* plane = Pc + (size_t)seg * PSEG;
#pragma unroll
    for (int jj = 0; jj < 4; ++jj) {
        int h = hb + jj*16 + lr;
        float bias = b2[seg*256 + h];
#pragma unroll
        for (int rr = 0; rr < 4; ++rr) {
            int s = sg*16 + lq*4 + rr;
            short4v o4;
#pragma unroll
            for (int i = 0; i < 4; ++i) {
                int m = (tg*8 + tj0 + i)*256 + s;
                float v = acc[i][jj][rr] + bias;
                float o;
                if (seg == 0)      o = plc[m] * fminf(fmaxf(v*(1.f/3.f) + 0.5f, 0.f), 1.f);
                else if (seg == 1) o = e2[m] * fmaxf(v, 0.f);
                else               o = __expf(v);
                o4[i] = (short)f2bf(o);
            }
            int idx = s*256 + h;
            *(short4v*)(plane + ((size_t)(idx >> 6)*TC + tg)*512 + (idx & 63)*8 + tj0) = o4;
        }
    }
}

// ---------------- k_scanconv: scan + 16-tap conv; depth-3 prefetch PINNED with
// sched_barrier(0); LDS transpose reduction (stride-65, conflict-free) replaces
// the 96-bpermute butterfly ----------------
__global__ __launch_bounds__(64, 1) void k_scanconv(const u16* __restrict__ Pc,
                                                    const float* __restrict__ ps,
                                                    const float* __restrict__ par,
                                                    const float* __restrict__ r,
                                                    float* __restrict__ out) {
    int g = blockIdx.x;                // 1024 groups of 64 (s,h) pairs
    int lane = threadIdx.x;
    int idx = g*64 + lane;
    int s = idx >> 8;
    __shared__ float s_ps[NT];
    __shared__ float sred[16*65];      // [j][lane] stride 65: writes & reads conflict-free
    for (int t = lane; t < NT; t += 64) s_ps[t] = ps[t*NS + s];
    float kp = par[idx], ks_ = par[65536+idx], kg = par[2*65536+idx],
          gp = par[3*65536+idx], gL = par[4*65536+idx], qb = par[5*65536+idx],
          ga = par[6*65536+idx];
    float rt[NR];
#pragma unroll
    for (int k = 0; k < NR; ++k) rt[k] = r[(size_t)idx*NR + k] * ga;
    __syncthreads();

    const u16* b0 = Pc + 0*PSEG + (size_t)g*TC*512 + lane*8;
    const u16* b1 = Pc + 1*PSEG + (size_t)g*TC*512 + lane*8;
    const u16* b2p= Pc + 2*PSEG + (size_t)g*TC*512 + lane*8;

    union U8 { short8 v; u16 u[8]; };
    U8 c0[6], c1[6], c2[6], c3[6];
#pragma unroll
    for (int hc = 0; hc < 2; ++hc) {
        c0[0 + hc].v = *(const short8*)(b0 + hc*512);
        c0[2 + hc].v = *(const short8*)(b1 + hc*512);
        c0[4 + hc].v = *(const short8*)(b2p + hc*512);
        c1[0 + hc].v = *(const short8*)(b0 + (2 + hc)*512);
        c1[2 + hc].v = *(const short8*)(b1 + (2 + hc)*512);
        c1[4 + hc].v = *(const short8*)(b2p + (2 + hc)*512);
        c2[0 + hc].v = *(const short8*)(b0 + (4 + hc)*512);
        c2[2 + hc].v = *(const short8*)(b1 + (4 + hc)*512);
        c2[4 + hc].v = *(const short8*)(b2p + (4 + hc)*512);
    }
    float Sf = 0.f, Ss = 0.f, Sg = 0.f;
    float qwin[16];
#pragma unroll
    for (int k = 0; k < 16; ++k) qwin[k] = 0.f;

    for (int blk = 0; blk < 23; ++blk) {
        int tbase = blk * 16;
        if (blk < 20) {                // depth-3 prefetch: chunk blk+3
            size_t o = (size_t)(2*blk + 6)*512;
#pragma unroll
            for (int hc = 0; hc < 2; ++hc) {
                c3[0 + hc].v = *(const short8*)(b0 + o + hc*512);
                c3[2 + hc].v = *(const short8*)(b1 + o + hc*512);
                c3[4 + hc].v = *(const short8*)(b2p + o + hc*512);
            }
        }
        __builtin_amdgcn_sched_barrier(0);   // pin prefetch issue BEFORE compute
        float cv[16];
#pragma unroll
        for (int j = 0; j < 16; ++j) cv[j] = 0.f;
#pragma unroll
        for (int j = 0; j < 16; ++j) {
            int t = tbase + j;
            if (t < NT) {
                float pl = bf2f(c0[0 + (j>>3)].u[j&7]);
                float ev = bf2f(c0[2 + (j>>3)].u[j&7]);
                float fm = bf2f(c0[4 + (j>>3)].u[j&7]);
                float fs = s_ps[t];
                float qf = fminf(Sf + fs, fm);
                Sf = fmaxf(Sf + fs - fm, 0.f);
                float H = fmaxf(Ss + pl + qf - ev, 0.f);
                float qp = fmaxf(kp * (H - gL), 0.f);
                float qsa = ks_ * fminf(H, gL);
                Ss = H - qp - qsa;
                float qsg = qsa * gp;
                float qs = qsa - qsg;
                float qg = kg * (Sg + qsg) + qb;
                Sg = (1.f - kg) * (Sg + qsg) - qb;
                float q = qp + qs + qg;
                qwin[j] = q;                 // slot t & 15 == j
                if (t >= 15) {
                    float c = 0.f;
#pragma unroll
                    for (int k = 0; k < 16; ++k) c += rt[k] * qwin[(j + 1 + k) & 15];
                    cv[j] = c;               // ga folded into rt
                }
            }
        }
#pragma unroll
        for (int pq = 0; pq < 6; ++pq) { c0[pq] = c1[pq]; c1[pq] = c2[pq]; c2[pq] = c3[pq]; }

        // LDS transpose reduction: Y[j] = sum over 64 lanes of cv[j]
#pragma unroll
        for (int j = 0; j < 16; ++j) sred[j*65 + lane] = cv[j];
        __syncthreads();               // 1 wave: cheap (lgkmcnt drain + nop barrier)
        {
            int j2 = lane & 15, q2 = lane >> 4;
            float p = 0.f;
#pragma unroll
            for (int i = 0; i < 16; ++i) p += sred[j2*65 + q2*16 + i];
            p += __shfl_xor(p, 16, 64);
            p += __shfl_xor(p, 32, 64);
            int tout = tbase + j2 - 15;
            if (lane < 16 && tout >= 0 && tout < TOUT)
                atomicAdd(out + tout*NS + s, p);
        }
        __syncthreads();               // sred reusable next iter
    }
}

// ---------------- launch ----------------
extern "C" void kernel_launch(void* const* d_in, const int* in_sizes, int n_in,
                              void* d_out, int out_size, void* d_ws, size_t ws_size,
                              hipStream_t stream) {
    const float* x   = (const float*)d_in[0];
    const float* xc  = (const float*)d_in[1];
    const float* fw1 = (const float*)d_in[2];
    const float* fb1 = (const float*)d_in[3];
    const float* fw2 = (const float*)d_in[4];
    const float* fb2 = (const float*)d_in[5];
    const float* tw1 = (const float*)d_in[6];
    const float* tb1 = (const float*)d_in[7];
    const float* tw2 = (const float*)d_in[8];
    const float* tb2 = (const float*)d_in[9];
    const float* rw1 = (const float*)d_in[10];
    const float* rb1 = (const float*)d_in[11];
    const float* rw2 = (const float*)d_in[12];
    const float* rb2 = (const float*)d_in[13];
    float* out = (float*)d_out;
    char* ws = (char*)d_ws;

    // workspace layout (bytes); peak = 202,326,016 (wlog in own region)
    constexpr size_t OFF_PS    = 0;              //   376,832 (padded to MPAD)
    constexpr size_t OFF_PLC   = 376832;         //   376,832
    constexpr size_t OFF_E2    = 753664;         //   376,832
    constexpr size_t OFF_PAR   = 1130496;        // 1,835,008
    constexpr size_t OFF_R     = 2965504;        // 4,194,304
    constexpr size_t OFF_W2TT  = 7159808;        //   393,216
    constexpr size_t OFF_H1B   = 7553024;        // 48,234,496 (MPAD rows)
    constexpr size_t OFF_PC    = 55787520;       // 144,703,488 -> 200,491,008
    constexpr size_t OFF_WLOG  = 200491008;      // 1,835,008 -> 202,326,016 (own region)
    // overlays inside Pc region (dead before k_g2p writes Pc):
    constexpr size_t OFF_W2TW  = OFF_PC + 0;           //   917,504
    constexpr size_t OFF_W2TR  = OFF_PC + 917504;      // 2,097,152
    constexpr size_t OFF_H1W   = OFF_PC + 3014656;     //   131,072
    constexpr size_t OFF_H1R   = OFF_PC + 3145728;     //   131,072

    float* ps    = (float*)(ws + OFF_PS);
    float* plc   = (float*)(ws + OFF_PLC);
    float* e2    = (float*)(ws + OFF_E2);
    float* par   = (float*)(ws + OFF_PAR);
    float* rbuf  = (float*)(ws + OFF_R);
    u16*   w2tT  = (u16*)(ws + OFF_W2TT);
    u16*   h1b   = (u16*)(ws + OFF_H1B);
    u16*   Pc    = (u16*)(ws + OFF_PC);
    float* wlog  = (float*)(ws + OFF_WLOG);
    u16*   w2tW  = (u16*)(ws + OFF_W2TW);
    u16*   w2tR  = (u16*)(ws + OFF_W2TR);
    u16*   h1W   = (u16*)(ws + OFF_H1W);
    u16*   h1R   = (u16*)(ws + OFF_H1R);

    k_prep     <<<813, 256, 0, stream>>>(x, ps, plc, e2, out,
                                         tw2, w2tT, fw2, w2tW, rw2, w2tR,
                                         xc, fw1, fb1, rw1, rb1, h1W, h1R);
    k_mid      <<<3036, 256, 0, stream>>>(h1W, w2tW, fb2, wlog,
                                          h1R, w2tR, rb2, rbuf,
                                          x, xc, tw1, tb1, h1b);
    k_g2p      <<<256 + TC*16*6, 256, 0, stream>>>(h1b, w2tT, tb2, plc, e2, Pc, wlog, par);
    k_scanconv <<<1024, 64, 0, stream>>>(Pc, ps, par, rbuf, out);
}